// Round 9
// baseline (197.128 us; speedup 1.0000x reference)
//
#include <hip/hip_runtime.h>
#include <math.h>
#include <stdint.h>

#define S    256
#define GN   128

typedef __attribute__((ext_vector_type(8))) short  short8;   // 8 bf16
typedef __attribute__((ext_vector_type(4))) float  floatx4;  // MFMA C/D

__device__ __forceinline__ unsigned short bf16_rtne(float f) {
    uint32_t u = __builtin_bit_cast(uint32_t, f);
    uint32_t r = (u + 0x7fffu + ((u >> 16) & 1u)) >> 16;
    return (unsigned short)r;
}
__device__ __forceinline__ unsigned short bf16_rhu(float f) {   // round-half-up
    return (unsigned short)((__builtin_bit_cast(uint32_t, f) + 0x8000u) >> 16);
}

// Single fused kernel (R9): per-block weight staging into LDS replaces the
// separate prep launch (R3-R8 showed ~65-78 us of launch/serialization gap
// vs ~0 for single-launch R1). One acc[4][4] array reused for both GEMMs
// caps AGPR at 64 so (256,3) fits with no spills (R8: facc+hacc as separate
// arrays -> 51.9 MB scratch traffic).
__global__ __launch_bounds__(256, 3)
void nerf_fused(const float* __restrict__ rays_o,
                const float* __restrict__ rays_d,
                const float* __restrict__ grid,
                const float* __restrict__ f_w1,
                const float* __restrict__ f_b1,
                const float* __restrict__ f_w2,
                const float* __restrict__ f_b2,
                const float* __restrict__ s_w,
                const float* __restrict__ s_b,
                const float* __restrict__ r_w1,
                const float* __restrict__ r_b1,
                const float* __restrict__ r_w2,
                const float* __restrict__ r_b2,
                float* __restrict__ out)
{
    // fh (32 KB): life 1 = f_w2 bf16 frag-order staging (first 16 KB);
    //             life 2 = feat/h bf16 [256 rows][64], XOR-swizzled.
    __shared__ unsigned short fh[256 * 64];
    __shared__ unsigned short rwL[4096];  // r_w1 bf16 frag-order (8 KB)
    __shared__ float w1p[512];            // interleaved {w1x,w1y,w1z,b1} per k
    __shared__ float ws2L[128];           // W2 @ s_w (fp32)
    __shared__ float b2sL;                // b2 . s_w + s_b
    __shared__ float aLds[S];
    __shared__ float maskLds[S];
    __shared__ float distLds[S];
    __shared__ float sWaveSum[4];
    __shared__ float sPart[4][3];

    const int tid   = threadIdx.x;
    const int ray   = blockIdx.x;
    const int lane  = tid & 63;
    const int wv    = tid >> 6;
    const int q     = lane >> 4;
    const int c     = lane & 15;
    const int mbase = wv * 64;

    // ---------------- Stage weights into LDS (cooperative, per block) --------
    // f_w2 -> bf16 in MFMA fragment order, into fh[0..8191]
    for (int i = tid; i < 8192; i += 256) {
        int k = i >> 6, n = i & 63;
        int pos = (((k >> 5) * 4 + (n >> 4)) * 64 + ((k >> 3) & 3) * 16 + (n & 15)) * 8 + (k & 7);
        fh[pos] = bf16_rtne(f_w2[i]);
    }
    // r_w1 (first 64 rows) -> bf16 frag order
    for (int i = tid; i < 4096; i += 256) {
        int k = i >> 6, n = i & 63;
        int pos = (((k >> 5) * 4 + (n >> 4)) * 64 + ((k >> 3) & 3) * 16 + (n & 15)) * 8 + (k & 7);
        rwL[pos] = bf16_rtne(r_w1[i]);
    }
    if (tid < 128) {
        w1p[tid * 4 + 0] = f_w1[tid];
        w1p[tid * 4 + 1] = f_w1[128 + tid];
        w1p[tid * 4 + 2] = f_w1[256 + tid];
        w1p[tid * 4 + 3] = f_b1[tid];
        const float* __restrict__ row = f_w2 + tid * 64;
        float acc = 0.0f;
        for (int n = 0; n < 64; ++n) acc += row[n] * s_w[n];
        ws2L[tid] = acc;
    } else if (tid == 128) {
        float acc = s_b[0];
        for (int n = 0; n < 64; ++n) acc += f_b2[n] * s_w[n];
        b2sL = acc;
    }

    // ---------------- Phase A: geometry + grid sample (thread = sample) ------
    const float stop = 1.0f - 1.0f / (float)(S + 2);
    const float step = stop / (float)S;
    float u0 = (float)tid * step;
    float u1 = (float)(tid + 1) * step;
    float t    = (u0 < 0.5f) ? 2.0f * u0 : 1.0f / (2.0f - 2.0f * u0);
    float tn_  = (u1 < 0.5f) ? 2.0f * u1 : 1.0f / (2.0f - 2.0f * u1);
    float dist = tn_ - t;

    float ox = rays_o[ray * 3 + 0], oy = rays_o[ray * 3 + 1], oz = rays_o[ray * 3 + 2];
    float dxv = rays_d[ray * 3 + 0], dyv = rays_d[ray * 3 + 1], dzv = rays_d[ray * 3 + 2];

    float px = ox + dxv * t, py = oy + dyv * t, pz = oz + dzv * t;
    float nrm = sqrtf(px * px + py * py + pz * pz);
    float scale = (nrm <= 1.0f) ? 0.5f : (2.0f - 1.0f / nrm) / nrm * 0.5f;
    float cx = px * scale, cy = py * scale, cz = pz * scale;

    float ix = ((cx + 1.0f) * (float)GN - 1.0f) * 0.5f;
    float iy = ((cy + 1.0f) * (float)GN - 1.0f) * 0.5f;
    float iz = ((cz + 1.0f) * (float)GN - 1.0f) * 0.5f;
    float fx0 = floorf(ix), fy0 = floorf(iy), fz0 = floorf(iz);
    float fx = ix - fx0, fy = iy - fy0, fz = iz - fz0;
    int x0 = (int)fx0, y0 = (int)fy0, z0 = (int)fz0;

    float occ = 0.0f;
    #pragma unroll
    for (int dzc = 0; dzc < 2; ++dzc)
    #pragma unroll
    for (int dyc = 0; dyc < 2; ++dyc)
    #pragma unroll
    for (int dxc = 0; dxc < 2; ++dxc) {
        int xc = x0 + dxc, yc = y0 + dyc, zc = z0 + dzc;
        float w = (dxc ? fx : 1.0f - fx) * (dyc ? fy : 1.0f - fy) * (dzc ? fz : 1.0f - fz);
        if (xc >= 0 && xc < GN && yc >= 0 && yc < GN && zc >= 0 && zc < GN)
            occ += w * grid[(zc * GN + yc) * GN + xc];
    }
    bool maskA = occ > 0.01f;
    maskLds[tid] = maskA ? 1.0f : 0.0f;
    distLds[tid] = dist;

    // coords of the A-fragment rows this thread covers (intra-wave broadcast)
    float cxs[4], cys[4], czs[4];
    #pragma unroll
    for (int tm = 0; tm < 4; ++tm) {
        int src = tm * 16 + c;
        cxs[tm] = __shfl(cx, src, 64);
        cys[tm] = __shfl(cy, src, 64);
        czs[tm] = __shfl(cz, src, 64);
    }
    __syncthreads();   // staging complete

    // ---------------- Phase B: feat GEMM (1-term bf16) + fp32 sigma dot ------
    floatx4 acc[4][4];          // reused for rgb GEMM in phase D (AGPR cap)
    {
        float b2v[4];
        #pragma unroll
        for (int tn = 0; tn < 4; ++tn) b2v[tn] = f_b2[tn * 16 + c];
        #pragma unroll
        for (int tm = 0; tm < 4; ++tm)
            #pragma unroll
            for (int tn = 0; tn < 4; ++tn) {
                floatx4 v; v[0] = b2v[tn]; v[1] = b2v[tn]; v[2] = b2v[tn]; v[3] = b2v[tn];
                acc[tm][tn] = v;
            }
    }
    float sig[4] = {0.0f, 0.0f, 0.0f, 0.0f};

    #pragma unroll 1
    for (int kc = 0; kc < 4; ++kc) {
        const int k0 = kc * 32 + q * 8;
        const float4* __restrict__ w1q = (const float4*)&w1p[k0 * 4];
        float ws2r[8];
        *(float4*)(ws2r)     = *(const float4*)&ws2L[k0];
        *(float4*)(ws2r + 4) = *(const float4*)&ws2L[k0 + 4];

        // A fragments: layer-1 recomputed from LDS pack; fp32 h feeds sigma dot
        short8 Ah[4];
        #pragma unroll
        for (int j = 0; j < 8; ++j) {
            float4 w = w1q[j];        // {w1x, w1y, w1z, b1} broadcast b128
            #pragma unroll
            for (int tm = 0; tm < 4; ++tm) {
                float h = w.w + cxs[tm] * w.x + cys[tm] * w.y + czs[tm] * w.z;
                h = fmaxf(h, 0.0f);
                sig[tm] += h * ws2r[j];
                Ah[tm][j] = (short)bf16_rhu(h);
            }
        }
        // B fragments from LDS (frag-order, 16 B/lane contiguous: conflict-free)
        const int bbase = kc * 2048 + lane * 8;
        #pragma unroll
        for (int tn = 0; tn < 4; ++tn) {
            short8 bh = *(const short8*)&fh[bbase + tn * 512];
            #pragma unroll
            for (int tm = 0; tm < 4; ++tm)
                acc[tm][tn] = __builtin_amdgcn_mfma_f32_16x16x32_bf16(Ah[tm], bh, acc[tm][tn], 0, 0, 0);
        }
    }
    __syncthreads();   // all bhi reads done before fh is overwritten

    // ---------------- Phase C: feat -> fh (swizzled bf16); sigma -> aLds -----
    #pragma unroll
    for (int tm = 0; tm < 4; ++tm)
        #pragma unroll
        for (int tn = 0; tn < 4; ++tn)
            #pragma unroll
            for (int reg = 0; reg < 4; ++reg) {
                int m = mbase + tm * 16 + q * 4 + reg;
                int n = tn * 16 + c;
                int idx = m * 64 + (((n >> 3) ^ (m & 7)) << 3) + (n & 7);
                fh[idx] = bf16_rhu(acc[tm][tn][reg]);
            }

    {
        // reduce sigma partials over the 4 q-groups (k-chunks)
        #pragma unroll
        for (int tm = 0; tm < 4; ++tm) {
            sig[tm] += __shfl_xor(sig[tm], 16);
            sig[tm] += __shfl_xor(sig[tm], 32);
        }
        float b2s = b2sL;
        if (q == 0) {
            #pragma unroll
            for (int tm = 0; tm < 4; ++tm) {
                int m = mbase + tm * 16 + c;
                float sa = sig[tm] + b2s;
                float sg = (maskLds[m] > 0.5f)
                         ? (fmaxf(sa, 0.0f) + __logf(1.0f + __expf(-fabsf(sa)))) : 0.0f;
                aLds[m] = -sg * distLds[m];
            }
        }
    }
    __builtin_amdgcn_wave_barrier();

    // ---------------- transmittance scan -------------------------------------
    float av = aLds[tid];
    float v = av;
    #pragma unroll
    for (int off = 1; off < 64; off <<= 1) {
        float u2 = __shfl_up(v, off);
        if (lane >= off) v += u2;
    }
    if (lane == 63) sWaveSum[wv] = v;
    __syncthreads();
    float basev = 0.0f;
    #pragma unroll
    for (int w = 0; w < 4; ++w) basev += (w < wv) ? sWaveSum[w] : 0.0f;
    float excl = __shfl_up(v, 1);
    if (lane == 0) excl = 0.0f;
    float cum    = basev + excl;
    float trans  = __expf(cum);
    float weight = trans * (1.0f - __expf(av));
    bool  mask2  = maskA && (trans > 1e-4f);

    // ---------------- Phase D: rgb-hidden GEMM (acc reused) ------------------
    float hd[4];
    #pragma unroll
    for (int tn = 0; tn < 4; ++tn) {
        int n = tn * 16 + c;
        hd[tn] = r_b1[n] + dxv * r_w1[64 * 64 + n] + dyv * r_w1[65 * 64 + n] + dzv * r_w1[66 * 64 + n];
    }

    short8 afr[4][2];
    #pragma unroll
    for (int tm = 0; tm < 4; ++tm)
        #pragma unroll
        for (int ks = 0; ks < 2; ++ks) {
            int m = mbase + tm * 16 + c;
            int gl = ks * 4 + q;
            afr[tm][ks] = *(const short8*)&fh[m * 64 + ((gl ^ (m & 7)) << 3)];
        }

    #pragma unroll
    for (int tm = 0; tm < 4; ++tm)
        #pragma unroll
        for (int tn = 0; tn < 4; ++tn) {
            floatx4 z; z[0] = 0.0f; z[1] = 0.0f; z[2] = 0.0f; z[3] = 0.0f;
            acc[tm][tn] = z;
        }
    #pragma unroll
    for (int ks = 0; ks < 2; ++ks)
        #pragma unroll
        for (int tn = 0; tn < 4; ++tn) {
            short8 rb = *(const short8*)&rwL[((ks * 4 + tn) * 64 + lane) * 8];
            #pragma unroll
            for (int tm = 0; tm < 4; ++tm)
                acc[tm][tn] = __builtin_amdgcn_mfma_f32_16x16x32_bf16(afr[tm][ks], rb, acc[tm][tn], 0, 0, 0);
        }

    __builtin_amdgcn_wave_barrier();
    #pragma unroll
    for (int tm = 0; tm < 4; ++tm)
        #pragma unroll
        for (int tn = 0; tn < 4; ++tn)
            #pragma unroll
            for (int reg = 0; reg < 4; ++reg) {
                int m = mbase + tm * 16 + q * 4 + reg;
                int n = tn * 16 + c;
                float hv = fmaxf(acc[tm][tn][reg] + hd[tn], 0.0f);
                int idx = m * 64 + (((n >> 3) ^ (m & 7)) << 3) + (n & 7);
                fh[idx] = bf16_rhu(hv);
            }
    __builtin_amdgcn_wave_barrier();

    // ---------------- Phase E: final 64->3 (thread = sample) -----------------
    float o0 = r_b2[0], o1 = r_b2[1], o2 = r_b2[2];
    const uint32_t* __restrict__ fr = (const uint32_t*)fh;
    #pragma unroll
    for (int gl = 0; gl < 8; ++gl) {
        int pg = gl ^ (tid & 7);
        uint4 pk = *(const uint4*)(fr + tid * 32 + pg * 4);
        uint32_t pw[4] = {pk.x, pk.y, pk.z, pk.w};
        #pragma unroll
        for (int tt = 0; tt < 4; ++tt) {
            float h0 = __builtin_bit_cast(float, pw[tt] << 16);
            float h1 = __builtin_bit_cast(float, pw[tt] & 0xffff0000u);
            int k = gl * 8 + 2 * tt;
            o0 += h0 * r_w2[k * 3 + 0] + h1 * r_w2[k * 3 + 3];
            o1 += h0 * r_w2[k * 3 + 1] + h1 * r_w2[k * 3 + 4];
            o2 += h0 * r_w2[k * 3 + 2] + h1 * r_w2[k * 3 + 5];
        }
    }
    float r = 0.0f, g = 0.0f, b = 0.0f;
    if (mask2) {
        r = weight / (1.0f + __expf(-o0));
        g = weight / (1.0f + __expf(-o1));
        b = weight / (1.0f + __expf(-o2));
    }

    #pragma unroll
    for (int off = 32; off > 0; off >>= 1) {
        r += __shfl_down(r, off);
        g += __shfl_down(g, off);
        b += __shfl_down(b, off);
    }
    if (lane == 0) { sPart[wv][0] = r; sPart[wv][1] = g; sPart[wv][2] = b; }
    __syncthreads();
    if (tid == 0) {
        out[ray * 3 + 0] = sPart[0][0] + sPart[1][0] + sPart[2][0] + sPart[3][0];
        out[ray * 3 + 1] = sPart[0][1] + sPart[1][1] + sPart[2][1] + sPart[3][1];
        out[ray * 3 + 2] = sPart[0][2] + sPart[1][2] + sPart[2][2] + sPart[3][2];
    }
}

extern "C" void kernel_launch(void* const* d_in, const int* in_sizes, int n_in,
                              void* d_out, int out_size, void* d_ws, size_t ws_size,
                              hipStream_t stream) {
    const int n_rays = in_sizes[0] / 3;   // 4096
    nerf_fused<<<n_rays, 256, 0, stream>>>(
        (const float*)d_in[0],  (const float*)d_in[1],  (const float*)d_in[2],
        (const float*)d_in[3],  (const float*)d_in[4],  (const float*)d_in[5],
        (const float*)d_in[6],  (const float*)d_in[7],  (const float*)d_in[8],
        (const float*)d_in[9],  (const float*)d_in[10], (const float*)d_in[11],
        (const float*)d_in[12], (float*)d_out);
}

// Round 11
// 191.271 us; speedup vs baseline: 1.0306x; 1.0306x over previous
//
#include <hip/hip_runtime.h>
#include <hip/hip_bf16.h>
#include <math.h>
#include <stdint.h>

#define S    256
#define GN   128

typedef __attribute__((ext_vector_type(8))) short  short8;   // 8 bf16
typedef __attribute__((ext_vector_type(4))) float  floatx4;  // MFMA C/D

// workspace layout (bytes)
#define WS_BHI 0          // ushort[4*4*64*8] = 16384 B  (f_w2 bf16, frag order)
#define WS_RW1 16384      // ushort[2*4*64*8] =  8192 B  (r_w1 bf16, frag order)
#define WS_B2S 24576      // float  (b2.s_w + s_b)
#define WS_WS2 24592      // float[128]  (W2 @ s_w, fp32)
#define WS_W1P 25104      // float4[128] interleaved {w1x,w1y,w1z,b1} = 2048 B

__device__ __forceinline__ unsigned short bf16_rtne(float f) {
    uint32_t u = __builtin_bit_cast(uint32_t, f);
    uint32_t r = (u + 0x7fffu + ((u >> 16) & 1u)) >> 16;
    return (unsigned short)r;
}
__device__ __forceinline__ unsigned short bf16_rhu(float f) {   // round-half-up
    return (unsigned short)((__builtin_bit_cast(uint32_t, f) + 0x8000u) >> 16);
}

// ---------- pre-pack kernel: weights -> bf16 in MFMA fragment order ----------
// R9 lesson: the dur_us-vs-counter gap (~65-78 us) is fixed harness overhead,
// independent of launch count -- the prep launch is effectively free, while
// per-block staging in the main kernel cost 16 us. Two-kernel it is.
__global__ __launch_bounds__(256)
void nerf_prep(const float* __restrict__ f_w1, const float* __restrict__ f_b1,
               const float* __restrict__ f_w2, const float* __restrict__ f_b2,
               const float* __restrict__ s_w,  const float* __restrict__ s_b,
               const float* __restrict__ r_w1, unsigned char* __restrict__ ws)
{
    const int tid = threadIdx.x;
    if (tid < 128) {                       // ws2 = W2 @ s_w  (fp32) -> global
        float acc = 0.0f;
        for (int n = 0; n < 64; ++n) acc += f_w2[tid * 64 + n] * s_w[n];
        ((float*)(ws + WS_WS2))[tid] = acc;
    } else if (tid == 128) {               // b2s = b2 . s_w + s_b
        float acc = s_b[0];
        for (int n = 0; n < 64; ++n) acc += f_b2[n] * s_w[n];
        *(float*)(ws + WS_B2S) = acc;
    }
    // layer-1 interleaved pack: entry k = {w1x[k], w1y[k], w1z[k], b1[k]}
    {
        float* w1pk = (float*)(ws + WS_W1P);
        for (int k = tid; k < 128; k += 256) {
            w1pk[k * 4 + 0] = f_w1[k];
            w1pk[k * 4 + 1] = f_w1[128 + k];
            w1pk[k * 4 + 2] = f_w1[256 + k];
            w1pk[k * 4 + 3] = f_b1[k];
        }
    }

    unsigned short* bhi = (unsigned short*)(ws + WS_BHI);
    for (int i = tid; i < 8192; i += 256) {
        int j = i & 7, L = (i >> 3) & 63, g = i >> 9;   // g = kc*4 + tn
        int tn = g & 3, kc = g >> 2;
        int q = L >> 4, cc = L & 15;
        int k = kc * 32 + q * 8 + j;
        bhi[i] = bf16_rtne(f_w2[k * 64 + tn * 16 + cc]);
    }
    unsigned short* rw = (unsigned short*)(ws + WS_RW1);
    for (int i = tid; i < 4096; i += 256) {
        int j = i & 7, L = (i >> 3) & 63, g = i >> 9;   // g = ks*4 + tn
        int tn = g & 3, ks = g >> 2;
        int q = L >> 4, cc = L & 15;
        int k = ks * 32 + q * 8 + j;
        rw[i] = bf16_rtne(r_w1[k * 64 + tn * 16 + cc]);
    }
}

// ---------------------------- main kernel -----------------------------------
// R11 = R8 structure + single acc[4][4] reused for both GEMMs (R9's validated
// spill cut: AGPR peak 128 -> 64) + A-frag packing via v_cvt_pk_bf16_f32
// (__float22bfloat162_rn; result moved with memcpy -- __hip_bfloat162 is not
// trivially copyable so bit_cast fails to compile, R10).
__global__ __launch_bounds__(256, 3)
void nerf_mfma(const float* __restrict__ rays_o,
               const float* __restrict__ rays_d,
               const float* __restrict__ grid,
               const float* __restrict__ f_b2,
               const float* __restrict__ r_w1,
               const float* __restrict__ r_b1,
               const float* __restrict__ r_w2,
               const float* __restrict__ r_b2,
               const unsigned char* __restrict__ ws,
               float* __restrict__ out)
{
    // fh: bf16 [256 rows][64], XOR-swizzled in 8-ushort groups: conflict-free b128
    __shared__ unsigned short fh[256 * 64];
    __shared__ float w1p[512];            // interleaved {w1x,w1y,w1z,b1} per k
    __shared__ float ws2L[128];           // W2 @ s_w (fp32)
    __shared__ float aLds[S];
    __shared__ float maskLds[S];
    __shared__ float distLds[S];
    __shared__ float sWaveSum[4];
    __shared__ float sPart[4][3];

    const int tid   = threadIdx.x;
    const int ray   = blockIdx.x;
    const int lane  = tid & 63;
    const int wv    = tid >> 6;
    const int q     = lane >> 4;
    const int c     = lane & 15;
    const int mbase = wv * 64;

    // stage layer-1 pack (2 KB) + ws2 (512 B) into LDS
    if (tid < 128) {
        ((float4*)w1p)[tid] = ((const float4*)(ws + WS_W1P))[tid];
        ws2L[tid] = ((const float*)(ws + WS_WS2))[tid];
    }

    // ---------------- Phase A: geometry + grid sample (thread = sample) ------
    const float stop = 1.0f - 1.0f / (float)(S + 2);
    const float step = stop / (float)S;
    float u0 = (float)tid * step;
    float u1 = (float)(tid + 1) * step;
    float t    = (u0 < 0.5f) ? 2.0f * u0 : 1.0f / (2.0f - 2.0f * u0);
    float tn_  = (u1 < 0.5f) ? 2.0f * u1 : 1.0f / (2.0f - 2.0f * u1);
    float dist = tn_ - t;

    float ox = rays_o[ray * 3 + 0], oy = rays_o[ray * 3 + 1], oz = rays_o[ray * 3 + 2];
    float dxv = rays_d[ray * 3 + 0], dyv = rays_d[ray * 3 + 1], dzv = rays_d[ray * 3 + 2];

    float px = ox + dxv * t, py = oy + dyv * t, pz = oz + dzv * t;
    float nrm = sqrtf(px * px + py * py + pz * pz);
    float scale = (nrm <= 1.0f) ? 0.5f : (2.0f - 1.0f / nrm) / nrm * 0.5f;
    float cx = px * scale, cy = py * scale, cz = pz * scale;

    float ix = ((cx + 1.0f) * (float)GN - 1.0f) * 0.5f;
    float iy = ((cy + 1.0f) * (float)GN - 1.0f) * 0.5f;
    float iz = ((cz + 1.0f) * (float)GN - 1.0f) * 0.5f;
    float fx0 = floorf(ix), fy0 = floorf(iy), fz0 = floorf(iz);
    float fx = ix - fx0, fy = iy - fy0, fz = iz - fz0;
    int x0 = (int)fx0, y0 = (int)fy0, z0 = (int)fz0;

    float occ = 0.0f;
    #pragma unroll
    for (int dzc = 0; dzc < 2; ++dzc)
    #pragma unroll
    for (int dyc = 0; dyc < 2; ++dyc)
    #pragma unroll
    for (int dxc = 0; dxc < 2; ++dxc) {
        int xc = x0 + dxc, yc = y0 + dyc, zc = z0 + dzc;
        float w = (dxc ? fx : 1.0f - fx) * (dyc ? fy : 1.0f - fy) * (dzc ? fz : 1.0f - fz);
        if (xc >= 0 && xc < GN && yc >= 0 && yc < GN && zc >= 0 && zc < GN)
            occ += w * grid[(zc * GN + yc) * GN + xc];
    }
    bool maskA = occ > 0.01f;
    maskLds[tid] = maskA ? 1.0f : 0.0f;
    distLds[tid] = dist;

    // coords of the A-fragment rows this thread covers (intra-wave broadcast)
    float cxs[4], cys[4], czs[4];
    #pragma unroll
    for (int tm = 0; tm < 4; ++tm) {
        int src = tm * 16 + c;
        cxs[tm] = __shfl(cx, src, 64);
        cys[tm] = __shfl(cy, src, 64);
        czs[tm] = __shfl(cz, src, 64);
    }
    __syncthreads();   // w1p / ws2L staged

    // ---------------- Phase B: feat GEMM (1-term bf16) + fp32 sigma dot ------
    floatx4 acc[4][4];          // reused for rgb GEMM in phase D (AGPR cap)
    {
        float b2v[4];
        #pragma unroll
        for (int tn = 0; tn < 4; ++tn) b2v[tn] = f_b2[tn * 16 + c];
        #pragma unroll
        for (int tm = 0; tm < 4; ++tm)
            #pragma unroll
            for (int tn = 0; tn < 4; ++tn) {
                floatx4 v; v[0] = b2v[tn]; v[1] = b2v[tn]; v[2] = b2v[tn]; v[3] = b2v[tn];
                acc[tm][tn] = v;
            }
    }
    float sig[4] = {0.0f, 0.0f, 0.0f, 0.0f};

    const unsigned short* __restrict__ bhiP = (const unsigned short*)(ws + WS_BHI);

    #pragma unroll 1
    for (int kc = 0; kc < 4; ++kc) {
        const int k0 = kc * 32 + q * 8;
        const float4* __restrict__ w1q = (const float4*)&w1p[k0 * 4];
        float ws2r[8];
        *(float4*)(ws2r)     = *(const float4*)&ws2L[k0];
        *(float4*)(ws2r + 4) = *(const float4*)&ws2L[k0 + 4];

        // A fragments: layer-1 recomputed from LDS pack; fp32 h feeds sigma
        // dot; pair-packed to bf16 via v_cvt_pk_bf16_f32 (RTNE).
        short8 Ah[4];
        #pragma unroll
        for (int tm = 0; tm < 4; ++tm) {
            uint32_t packed[4];
            #pragma unroll
            for (int p = 0; p < 4; ++p) {
                float4 wA = w1q[2 * p];
                float4 wB = w1q[2 * p + 1];
                float h0 = wA.w + cxs[tm] * wA.x + cys[tm] * wA.y + czs[tm] * wA.z;
                float h1 = wB.w + cxs[tm] * wB.x + cys[tm] * wB.y + czs[tm] * wB.z;
                h0 = fmaxf(h0, 0.0f);
                h1 = fmaxf(h1, 0.0f);
                sig[tm] += h0 * ws2r[2 * p] + h1 * ws2r[2 * p + 1];
                float2 hh; hh.x = h0; hh.y = h1;
                __hip_bfloat162 pk = __float22bfloat162_rn(hh);
                uint32_t w32;
                __builtin_memcpy(&w32, &pk, 4);
                packed[p] = w32;
            }
            uint4 v4 = {packed[0], packed[1], packed[2], packed[3]};
            Ah[tm] = __builtin_bit_cast(short8, v4);
        }
        // B fragments: straight dwordx4 loads from ws, zero conversion
        const int bbase = (kc * 4) * 512 + lane * 8;
        #pragma unroll
        for (int tn = 0; tn < 4; ++tn) {
            short8 bh = *(const short8*)(bhiP + bbase + tn * 512);
            #pragma unroll
            for (int tm = 0; tm < 4; ++tm)
                acc[tm][tn] = __builtin_amdgcn_mfma_f32_16x16x32_bf16(Ah[tm], bh, acc[tm][tn], 0, 0, 0);
        }
    }

    // ---------------- Phase C: feat -> fh (swizzled bf16); sigma -> aLds -----
    #pragma unroll
    for (int tm = 0; tm < 4; ++tm)
        #pragma unroll
        for (int tn = 0; tn < 4; ++tn)
            #pragma unroll
            for (int reg = 0; reg < 4; ++reg) {
                int m = mbase + tm * 16 + q * 4 + reg;
                int n = tn * 16 + c;
                int idx = m * 64 + (((n >> 3) ^ (m & 7)) << 3) + (n & 7);
                fh[idx] = bf16_rhu(acc[tm][tn][reg]);
            }

    {
        // reduce sigma partials over the 4 q-groups (k-chunks)
        #pragma unroll
        for (int tm = 0; tm < 4; ++tm) {
            sig[tm] += __shfl_xor(sig[tm], 16);
            sig[tm] += __shfl_xor(sig[tm], 32);
        }
        float b2s = *(const float*)(ws + WS_B2S);
        if (q == 0) {
            #pragma unroll
            for (int tm = 0; tm < 4; ++tm) {
                int m = mbase + tm * 16 + c;
                float sa = sig[tm] + b2s;
                float sg = (maskLds[m] > 0.5f)
                         ? (fmaxf(sa, 0.0f) + __logf(1.0f + __expf(-fabsf(sa)))) : 0.0f;
                aLds[m] = -sg * distLds[m];
            }
        }
    }
    __builtin_amdgcn_wave_barrier();

    // ---------------- transmittance scan -------------------------------------
    float av = aLds[tid];
    float v = av;
    #pragma unroll
    for (int off = 1; off < 64; off <<= 1) {
        float u2 = __shfl_up(v, off);
        if (lane >= off) v += u2;
    }
    if (lane == 63) sWaveSum[wv] = v;
    __syncthreads();
    float basev = 0.0f;
    #pragma unroll
    for (int w = 0; w < 4; ++w) basev += (w < wv) ? sWaveSum[w] : 0.0f;
    float excl = __shfl_up(v, 1);
    if (lane == 0) excl = 0.0f;
    float cum    = basev + excl;
    float trans  = __expf(cum);
    float weight = trans * (1.0f - __expf(av));
    bool  mask2  = maskA && (trans > 1e-4f);

    // ---------------- Phase D: rgb-hidden GEMM (acc reused) ------------------
    float hd[4];
    #pragma unroll
    for (int tn = 0; tn < 4; ++tn) {
        int n = tn * 16 + c;
        hd[tn] = r_b1[n] + dxv * r_w1[64 * 64 + n] + dyv * r_w1[65 * 64 + n] + dzv * r_w1[66 * 64 + n];
    }

    short8 afr[4][2];
    #pragma unroll
    for (int tm = 0; tm < 4; ++tm)
        #pragma unroll
        for (int ks = 0; ks < 2; ++ks) {
            int m = mbase + tm * 16 + c;
            int gl = ks * 4 + q;
            afr[tm][ks] = *(const short8*)&fh[m * 64 + ((gl ^ (m & 7)) << 3)];
        }

    #pragma unroll
    for (int tm = 0; tm < 4; ++tm)
        #pragma unroll
        for (int tn = 0; tn < 4; ++tn) {
            floatx4 z; z[0] = 0.0f; z[1] = 0.0f; z[2] = 0.0f; z[3] = 0.0f;
            acc[tm][tn] = z;
        }
    const unsigned short* __restrict__ rwP = (const unsigned short*)(ws + WS_RW1);
    #pragma unroll
    for (int ks = 0; ks < 2; ++ks)
        #pragma unroll
        for (int tn = 0; tn < 4; ++tn) {
            short8 rb = *(const short8*)(rwP + ((ks * 4 + tn) * 64 + lane) * 8);
            #pragma unroll
            for (int tm = 0; tm < 4; ++tm)
                acc[tm][tn] = __builtin_amdgcn_mfma_f32_16x16x32_bf16(afr[tm][ks], rb, acc[tm][tn], 0, 0, 0);
        }

    __builtin_amdgcn_wave_barrier();
    #pragma unroll
    for (int tm = 0; tm < 4; ++tm)
        #pragma unroll
        for (int tn = 0; tn < 4; ++tn)
            #pragma unroll
            for (int reg = 0; reg < 4; ++reg) {
                int m = mbase + tm * 16 + q * 4 + reg;
                int n = tn * 16 + c;
                float hv = fmaxf(acc[tm][tn][reg] + hd[tn], 0.0f);
                int idx = m * 64 + (((n >> 3) ^ (m & 7)) << 3) + (n & 7);
                fh[idx] = bf16_rhu(hv);
            }
    __builtin_amdgcn_wave_barrier();

    // ---------------- Phase E: final 64->3 (thread = sample) -----------------
    float o0 = r_b2[0], o1 = r_b2[1], o2 = r_b2[2];
    const uint32_t* __restrict__ fr = (const uint32_t*)fh;
    #pragma unroll
    for (int gl = 0; gl < 8; ++gl) {
        int pg = gl ^ (tid & 7);
        uint4 pk = *(const uint4*)(fr + tid * 32 + pg * 4);
        uint32_t pw[4] = {pk.x, pk.y, pk.z, pk.w};
        #pragma unroll
        for (int tt = 0; tt < 4; ++tt) {
            float h0 = __builtin_bit_cast(float, pw[tt] << 16);
            float h1 = __builtin_bit_cast(float, pw[tt] & 0xffff0000u);
            int k = gl * 8 + 2 * tt;
            o0 += h0 * r_w2[k * 3 + 0] + h1 * r_w2[k * 3 + 3];
            o1 += h0 * r_w2[k * 3 + 1] + h1 * r_w2[k * 3 + 4];
            o2 += h0 * r_w2[k * 3 + 2] + h1 * r_w2[k * 3 + 5];
        }
    }
    float r = 0.0f, g = 0.0f, b = 0.0f;
    if (mask2) {
        r = weight / (1.0f + __expf(-o0));
        g = weight / (1.0f + __expf(-o1));
        b = weight / (1.0f + __expf(-o2));
    }

    #pragma unroll
    for (int off = 32; off > 0; off >>= 1) {
        r += __shfl_down(r, off);
        g += __shfl_down(g, off);
        b += __shfl_down(b, off);
    }
    if (lane == 0) { sPart[wv][0] = r; sPart[wv][1] = g; sPart[wv][2] = b; }
    __syncthreads();
    if (tid == 0) {
        out[ray * 3 + 0] = sPart[0][0] + sPart[1][0] + sPart[2][0] + sPart[3][0];
        out[ray * 3 + 1] = sPart[0][1] + sPart[1][1] + sPart[2][1] + sPart[3][1];
        out[ray * 3 + 2] = sPart[0][2] + sPart[1][2] + sPart[2][2] + sPart[3][2];
    }
}

extern "C" void kernel_launch(void* const* d_in, const int* in_sizes, int n_in,
                              void* d_out, int out_size, void* d_ws, size_t ws_size,
                              hipStream_t stream) {
    const int n_rays = in_sizes[0] / 3;   // 4096
    nerf_prep<<<1, 256, 0, stream>>>(
        (const float*)d_in[3], (const float*)d_in[4], (const float*)d_in[5],
        (const float*)d_in[6], (const float*)d_in[7], (const float*)d_in[8],
        (const float*)d_in[9], (unsigned char*)d_ws);
    nerf_mfma<<<n_rays, 256, 0, stream>>>(
        (const float*)d_in[0],  (const float*)d_in[1],  (const float*)d_in[2],
        (const float*)d_in[6],  (const float*)d_in[9],  (const float*)d_in[10],
        (const float*)d_in[11], (const float*)d_in[12],
        (const unsigned char*)d_ws, (float*)d_out);
}

// Round 12
// 177.315 us; speedup vs baseline: 1.1117x; 1.0787x over previous
//
#include <hip/hip_runtime.h>
#include <hip/hip_bf16.h>
#include <math.h>
#include <stdint.h>

#define S    256
#define GN   128

typedef __attribute__((ext_vector_type(8))) short  short8;   // 8 bf16
typedef __attribute__((ext_vector_type(4))) float  floatx4;  // MFMA C/D
typedef __attribute__((ext_vector_type(2))) float  float2v;  // v_pk_*_f32 pair

// workspace layout (bytes)
#define WS_BHI 0          // ushort[4*4*64*8] = 16384 B  (f_w2 bf16, frag order)
#define WS_RW1 16384      // ushort[2*4*64*8] =  8192 B  (r_w1 bf16, frag order)
#define WS_B2S 24576      // float  (b2.s_w + s_b)
#define WS_WS2 24592      // float[128]  (W2 @ s_w, fp32)
#define WS_W1P 25104      // float[64*8] pair-interleaved layer-1 = 2048 B

__device__ __forceinline__ unsigned short bf16_rtne(float f) {
    uint32_t u = __builtin_bit_cast(uint32_t, f);
    uint32_t r = (u + 0x7fffu + ((u >> 16) & 1u)) >> 16;
    return (unsigned short)r;
}
__device__ __forceinline__ uint32_t cvt_pk_bf16(float a, float b) {
    float2 hh; hh.x = a; hh.y = b;
    __hip_bfloat162 pk = __float22bfloat162_rn(hh);   // v_cvt_pk_bf16_f32
    uint32_t u; __builtin_memcpy(&u, &pk, 4);
    return u;
}

// ---------- pre-pack kernel: weights -> bf16 in MFMA fragment order ----------
// R9 lesson: the dur-vs-counter gap (~77 us) is fixed harness overhead;
// the prep launch is effectively free. Two-kernel structure.
__global__ __launch_bounds__(256)
void nerf_prep(const float* __restrict__ f_w1, const float* __restrict__ f_b1,
               const float* __restrict__ f_w2, const float* __restrict__ f_b2,
               const float* __restrict__ s_w,  const float* __restrict__ s_b,
               const float* __restrict__ r_w1, unsigned char* __restrict__ ws)
{
    const int tid = threadIdx.x;
    if (tid < 128) {                       // ws2 = W2 @ s_w  (fp32) -> global
        float acc = 0.0f;
        for (int n = 0; n < 64; ++n) acc += f_w2[tid * 64 + n] * s_w[n];
        ((float*)(ws + WS_WS2))[tid] = acc;
    } else if (tid == 128) {               // b2s = b2 . s_w + s_b
        float acc = s_b[0];
        for (int n = 0; n < 64; ++n) acc += f_b2[n] * s_w[n];
        *(float*)(ws + WS_B2S) = acc;
    }
    // layer-1 pair-interleaved pack: pair pp covers k=2pp,2pp+1:
    //   {wx0,wx1, wy0,wy1, wz0,wz1, b0,b1}  (aligned float2 pairs for v_pk_fma)
    {
        float* w1pk = (float*)(ws + WS_W1P);
        for (int pp = tid; pp < 64; pp += 256) {
            int k0 = 2 * pp, k1 = 2 * pp + 1;
            w1pk[pp * 8 + 0] = f_w1[k0];       w1pk[pp * 8 + 1] = f_w1[k1];
            w1pk[pp * 8 + 2] = f_w1[128 + k0]; w1pk[pp * 8 + 3] = f_w1[128 + k1];
            w1pk[pp * 8 + 4] = f_w1[256 + k0]; w1pk[pp * 8 + 5] = f_w1[256 + k1];
            w1pk[pp * 8 + 6] = f_b1[k0];       w1pk[pp * 8 + 7] = f_b1[k1];
        }
    }

    unsigned short* bhi = (unsigned short*)(ws + WS_BHI);
    for (int i = tid; i < 8192; i += 256) {
        int j = i & 7, L = (i >> 3) & 63, g = i >> 9;   // g = kc*4 + tn
        int tn = g & 3, kc = g >> 2;
        int q = L >> 4, cc = L & 15;
        int k = kc * 32 + q * 8 + j;
        bhi[i] = bf16_rtne(f_w2[k * 64 + tn * 16 + cc]);
    }
    unsigned short* rw = (unsigned short*)(ws + WS_RW1);
    for (int i = tid; i < 4096; i += 256) {
        int j = i & 7, L = (i >> 3) & 63, g = i >> 9;   // g = ks*4 + tn
        int tn = g & 3, ks = g >> 2;
        int q = L >> 4, cc = L & 15;
        int k = ks * 32 + q * 8 + j;
        rw[i] = bf16_rtne(r_w1[k * 64 + tn * 16 + cc]);
    }
}

// ---------------------------- main kernel -----------------------------------
// R12: VALU compression via packed fp32 (R11 verified v_cvt_pk_bf16_f32):
//  - A-gen: k-pair packed v_pk_fma/v_pk_max + packed sigma dot (6 ops/2 vals
//    vs 11 scalar), w1 pre-packed pair-interleaved for aligned VGPR pairs
//  - phase C / D epilogues: cvt_pk + shift per pair instead of 2x rhu
//  - phase E: (h0,h1)-pair pk_fma accumulate
// ~-570 VALU inst/thread of ~1330 (R11 counter arithmetic).
__global__ __launch_bounds__(256, 3)
void nerf_mfma(const float* __restrict__ rays_o,
               const float* __restrict__ rays_d,
               const float* __restrict__ grid,
               const float* __restrict__ f_b2,
               const float* __restrict__ r_w1,
               const float* __restrict__ r_b1,
               const float* __restrict__ r_w2,
               const float* __restrict__ r_b2,
               const unsigned char* __restrict__ ws,
               float* __restrict__ out)
{
    // fh: bf16 [256 rows][64], XOR-swizzled in 8-ushort groups: conflict-free b128
    __shared__ unsigned short fh[256 * 64];
    __shared__ float w1p[512];            // pair-interleaved layer-1
    __shared__ float ws2L[128];           // W2 @ s_w (fp32)
    __shared__ float aLds[S];
    __shared__ float maskLds[S];
    __shared__ float distLds[S];
    __shared__ float sWaveSum[4];
    __shared__ float sPart[4][3];

    const int tid   = threadIdx.x;
    const int ray   = blockIdx.x;
    const int lane  = tid & 63;
    const int wv    = tid >> 6;
    const int q     = lane >> 4;
    const int c     = lane & 15;
    const int mbase = wv * 64;

    // stage layer-1 pack (2 KB) + ws2 (512 B) into LDS
    if (tid < 128) {
        ((float4*)w1p)[tid] = ((const float4*)(ws + WS_W1P))[tid];
        ws2L[tid] = ((const float*)(ws + WS_WS2))[tid];
    }

    // ---------------- Phase A: geometry + grid sample (thread = sample) ------
    const float stop = 1.0f - 1.0f / (float)(S + 2);
    const float step = stop / (float)S;
    float u0 = (float)tid * step;
    float u1 = (float)(tid + 1) * step;
    float t    = (u0 < 0.5f) ? 2.0f * u0 : 1.0f / (2.0f - 2.0f * u0);
    float tn_  = (u1 < 0.5f) ? 2.0f * u1 : 1.0f / (2.0f - 2.0f * u1);
    float dist = tn_ - t;

    float ox = rays_o[ray * 3 + 0], oy = rays_o[ray * 3 + 1], oz = rays_o[ray * 3 + 2];
    float dxv = rays_d[ray * 3 + 0], dyv = rays_d[ray * 3 + 1], dzv = rays_d[ray * 3 + 2];

    float px = ox + dxv * t, py = oy + dyv * t, pz = oz + dzv * t;
    float nrm = sqrtf(px * px + py * py + pz * pz);
    float scale = (nrm <= 1.0f) ? 0.5f : (2.0f - 1.0f / nrm) / nrm * 0.5f;
    float cx = px * scale, cy = py * scale, cz = pz * scale;

    float ix = ((cx + 1.0f) * (float)GN - 1.0f) * 0.5f;
    float iy = ((cy + 1.0f) * (float)GN - 1.0f) * 0.5f;
    float iz = ((cz + 1.0f) * (float)GN - 1.0f) * 0.5f;
    float fx0 = floorf(ix), fy0 = floorf(iy), fz0 = floorf(iz);
    float fx = ix - fx0, fy = iy - fy0, fz = iz - fz0;
    int x0 = (int)fx0, y0 = (int)fy0, z0 = (int)fz0;

    float occ = 0.0f;
    #pragma unroll
    for (int dzc = 0; dzc < 2; ++dzc)
    #pragma unroll
    for (int dyc = 0; dyc < 2; ++dyc)
    #pragma unroll
    for (int dxc = 0; dxc < 2; ++dxc) {
        int xc = x0 + dxc, yc = y0 + dyc, zc = z0 + dzc;
        float w = (dxc ? fx : 1.0f - fx) * (dyc ? fy : 1.0f - fy) * (dzc ? fz : 1.0f - fz);
        if (xc >= 0 && xc < GN && yc >= 0 && yc < GN && zc >= 0 && zc < GN)
            occ += w * grid[(zc * GN + yc) * GN + xc];
    }
    bool maskA = occ > 0.01f;
    maskLds[tid] = maskA ? 1.0f : 0.0f;
    distLds[tid] = dist;

    // coords of the A-fragment rows this thread covers (intra-wave broadcast)
    float cxs[4], cys[4], czs[4];
    #pragma unroll
    for (int tm = 0; tm < 4; ++tm) {
        int src = tm * 16 + c;
        cxs[tm] = __shfl(cx, src, 64);
        cys[tm] = __shfl(cy, src, 64);
        czs[tm] = __shfl(cz, src, 64);
    }
    __syncthreads();   // w1p / ws2L staged

    // ---------------- Phase B: feat GEMM (1-term bf16) + packed sigma dot ----
    floatx4 acc[4][4];          // reused for rgb GEMM in phase D
    {
        float b2v[4];
        #pragma unroll
        for (int tn = 0; tn < 4; ++tn) b2v[tn] = f_b2[tn * 16 + c];
        #pragma unroll
        for (int tm = 0; tm < 4; ++tm)
            #pragma unroll
            for (int tn = 0; tn < 4; ++tn) {
                floatx4 v; v[0] = b2v[tn]; v[1] = b2v[tn]; v[2] = b2v[tn]; v[3] = b2v[tn];
                acc[tm][tn] = v;
            }
    }
    float2v sig2[4];
    #pragma unroll
    for (int tm = 0; tm < 4; ++tm) { sig2[tm][0] = 0.0f; sig2[tm][1] = 0.0f; }

    const unsigned short* __restrict__ bhiP = (const unsigned short*)(ws + WS_BHI);

    #pragma unroll 1
    for (int kc = 0; kc < 4; ++kc) {
        const int k0  = kc * 32 + q * 8;     // first k of this lane's chunk
        const int pp0 = kc * 16 + q * 4;     // first k-pair index
        const float4* __restrict__ w1q4 = (const float4*)&w1p[pp0 * 8];
        float ws2r[8];
        *(float4*)(ws2r)     = *(const float4*)&ws2L[k0];
        *(float4*)(ws2r + 4) = *(const float4*)&ws2L[k0 + 4];

        // A fragments: layer-1 on packed fp32 pairs; packed sigma accumulate;
        // pair-convert to bf16 via v_cvt_pk_bf16_f32.
        uint32_t packed[4][4];
        #pragma unroll
        for (int p = 0; p < 4; ++p) {
            float4 q0 = w1q4[2 * p];         // {wx0,wx1, wy0,wy1}
            float4 q1 = w1q4[2 * p + 1];     // {wz0,wz1, b0, b1}
            float2v wx2 = {q0.x, q0.y};
            float2v wy2 = {q0.z, q0.w};
            float2v wz2 = {q1.x, q1.y};
            float2v bb2 = {q1.z, q1.w};
            float2v wsp = {ws2r[2 * p], ws2r[2 * p + 1]};
            #pragma unroll
            for (int tm = 0; tm < 4; ++tm) {
                float2v h2 = bb2;
                h2 = __builtin_elementwise_fma((float2v){cxs[tm], cxs[tm]}, wx2, h2);
                h2 = __builtin_elementwise_fma((float2v){cys[tm], cys[tm]}, wy2, h2);
                h2 = __builtin_elementwise_fma((float2v){czs[tm], czs[tm]}, wz2, h2);
                h2 = __builtin_elementwise_max(h2, (float2v){0.0f, 0.0f});
                sig2[tm] = __builtin_elementwise_fma(h2, wsp, sig2[tm]);
                packed[tm][p] = cvt_pk_bf16(h2[0], h2[1]);
            }
        }
        short8 Ah[4];
        #pragma unroll
        for (int tm = 0; tm < 4; ++tm) {
            uint4 v4 = {packed[tm][0], packed[tm][1], packed[tm][2], packed[tm][3]};
            Ah[tm] = __builtin_bit_cast(short8, v4);
        }
        // B fragments: straight dwordx4 loads from ws, zero conversion
        const int bbase = (kc * 4) * 512 + lane * 8;
        #pragma unroll
        for (int tn = 0; tn < 4; ++tn) {
            short8 bh = *(const short8*)(bhiP + bbase + tn * 512);
            #pragma unroll
            for (int tm = 0; tm < 4; ++tm)
                acc[tm][tn] = __builtin_amdgcn_mfma_f32_16x16x32_bf16(Ah[tm], bh, acc[tm][tn], 0, 0, 0);
        }
    }

    // ---------------- Phase C: feat -> fh (cvt_pk pairs); sigma -> aLds ------
    #pragma unroll
    for (int tm = 0; tm < 4; ++tm)
        #pragma unroll
        for (int tn = 0; tn < 4; ++tn)
            #pragma unroll
            for (int pr = 0; pr < 2; ++pr) {
                uint32_t u = cvt_pk_bf16(acc[tm][tn][2 * pr], acc[tm][tn][2 * pr + 1]);
                int n  = tn * 16 + c;
                int m0 = mbase + tm * 16 + q * 4 + 2 * pr;
                int m1 = m0 + 1;
                int i0 = m0 * 64 + (((n >> 3) ^ (m0 & 7)) << 3) + (n & 7);
                int i1 = m1 * 64 + (((n >> 3) ^ (m1 & 7)) << 3) + (n & 7);
                fh[i0] = (unsigned short)u;
                fh[i1] = (unsigned short)(u >> 16);
            }

    {
        float sig[4];
        #pragma unroll
        for (int tm = 0; tm < 4; ++tm) {
            float s = sig2[tm][0] + sig2[tm][1];
            s += __shfl_xor(s, 16);
            s += __shfl_xor(s, 32);
            sig[tm] = s;
        }
        float b2s = *(const float*)(ws + WS_B2S);
        if (q == 0) {
            #pragma unroll
            for (int tm = 0; tm < 4; ++tm) {
                int m = mbase + tm * 16 + c;
                float sa = sig[tm] + b2s;
                float sg = (maskLds[m] > 0.5f)
                         ? (fmaxf(sa, 0.0f) + __logf(1.0f + __expf(-fabsf(sa)))) : 0.0f;
                aLds[m] = -sg * distLds[m];
            }
        }
    }
    __builtin_amdgcn_wave_barrier();

    // ---------------- transmittance scan -------------------------------------
    float av = aLds[tid];
    float v = av;
    #pragma unroll
    for (int off = 1; off < 64; off <<= 1) {
        float u2 = __shfl_up(v, off);
        if (lane >= off) v += u2;
    }
    if (lane == 63) sWaveSum[wv] = v;
    __syncthreads();
    float basev = 0.0f;
    #pragma unroll
    for (int w = 0; w < 4; ++w) basev += (w < wv) ? sWaveSum[w] : 0.0f;
    float excl = __shfl_up(v, 1);
    if (lane == 0) excl = 0.0f;
    float cum    = basev + excl;
    float trans  = __expf(cum);
    float weight = trans * (1.0f - __expf(av));
    bool  mask2  = maskA && (trans > 1e-4f);

    // ---------------- Phase D: rgb-hidden GEMM (acc reused) ------------------
    float hd[4];
    #pragma unroll
    for (int tn = 0; tn < 4; ++tn) {
        int n = tn * 16 + c;
        hd[tn] = r_b1[n] + dxv * r_w1[64 * 64 + n] + dyv * r_w1[65 * 64 + n] + dzv * r_w1[66 * 64 + n];
    }

    short8 afr[4][2];
    #pragma unroll
    for (int tm = 0; tm < 4; ++tm)
        #pragma unroll
        for (int ks = 0; ks < 2; ++ks) {
            int m = mbase + tm * 16 + c;
            int gl = ks * 4 + q;
            afr[tm][ks] = *(const short8*)&fh[m * 64 + ((gl ^ (m & 7)) << 3)];
        }

    #pragma unroll
    for (int tm = 0; tm < 4; ++tm)
        #pragma unroll
        for (int tn = 0; tn < 4; ++tn) {
            floatx4 z; z[0] = 0.0f; z[1] = 0.0f; z[2] = 0.0f; z[3] = 0.0f;
            acc[tm][tn] = z;
        }
    const unsigned short* __restrict__ rwP = (const unsigned short*)(ws + WS_RW1);
    #pragma unroll
    for (int ks = 0; ks < 2; ++ks)
        #pragma unroll
        for (int tn = 0; tn < 4; ++tn) {
            short8 rb = *(const short8*)(rwP + ((ks * 4 + tn) * 64 + lane) * 8);
            #pragma unroll
            for (int tm = 0; tm < 4; ++tm)
                acc[tm][tn] = __builtin_amdgcn_mfma_f32_16x16x32_bf16(afr[tm][ks], rb, acc[tm][tn], 0, 0, 0);
        }

    __builtin_amdgcn_wave_barrier();
    #pragma unroll
    for (int tm = 0; tm < 4; ++tm)
        #pragma unroll
        for (int tn = 0; tn < 4; ++tn)
            #pragma unroll
            for (int pr = 0; pr < 2; ++pr) {
                float v0 = fmaxf(acc[tm][tn][2 * pr]     + hd[tn], 0.0f);
                float v1 = fmaxf(acc[tm][tn][2 * pr + 1] + hd[tn], 0.0f);
                uint32_t u = cvt_pk_bf16(v0, v1);
                int n  = tn * 16 + c;
                int m0 = mbase + tm * 16 + q * 4 + 2 * pr;
                int m1 = m0 + 1;
                int i0 = m0 * 64 + (((n >> 3) ^ (m0 & 7)) << 3) + (n & 7);
                int i1 = m1 * 64 + (((n >> 3) ^ (m1 & 7)) << 3) + (n & 7);
                fh[i0] = (unsigned short)u;
                fh[i1] = (unsigned short)(u >> 16);
            }
    __builtin_amdgcn_wave_barrier();

    // ---------------- Phase E: final 64->3 (thread = sample, pk_fma pairs) ---
    float2v o0v = {0.0f, 0.0f}, o1v = {0.0f, 0.0f}, o2v = {0.0f, 0.0f};
    const uint32_t* __restrict__ fr = (const uint32_t*)fh;
    #pragma unroll
    for (int gl = 0; gl < 8; ++gl) {
        int pg = gl ^ (tid & 7);
        uint4 pk = *(const uint4*)(fr + tid * 32 + pg * 4);
        uint32_t pw[4] = {pk.x, pk.y, pk.z, pk.w};
        #pragma unroll
        for (int tt = 0; tt < 4; ++tt) {
            float h0 = __builtin_bit_cast(float, pw[tt] << 16);
            float h1 = __builtin_bit_cast(float, pw[tt] & 0xffff0000u);
            int k = gl * 8 + 2 * tt;
            float2v hp = {h0, h1};
            o0v = __builtin_elementwise_fma(hp, (float2v){r_w2[k * 3 + 0], r_w2[k * 3 + 3]}, o0v);
            o1v = __builtin_elementwise_fma(hp, (float2v){r_w2[k * 3 + 1], r_w2[k * 3 + 4]}, o1v);
            o2v = __builtin_elementwise_fma(hp, (float2v){r_w2[k * 3 + 2], r_w2[k * 3 + 5]}, o2v);
        }
    }
    float o0 = r_b2[0] + o0v[0] + o0v[1];
    float o1 = r_b2[1] + o1v[0] + o1v[1];
    float o2 = r_b2[2] + o2v[0] + o2v[1];

    float r = 0.0f, g = 0.0f, b = 0.0f;
    if (mask2) {
        r = weight / (1.0f + __expf(-o0));
        g = weight / (1.0f + __expf(-o1));
        b = weight / (1.0f + __expf(-o2));
    }

    #pragma unroll
    for (int off = 32; off > 0; off >>= 1) {
        r += __shfl_down(r, off);
        g += __shfl_down(g, off);
        b += __shfl_down(b, off);
    }
    if (lane == 0) { sPart[wv][0] = r; sPart[wv][1] = g; sPart[wv][2] = b; }
    __syncthreads();
    if (tid == 0) {
        out[ray * 3 + 0] = sPart[0][0] + sPart[1][0] + sPart[2][0] + sPart[3][0];
        out[ray * 3 + 1] = sPart[0][1] + sPart[1][1] + sPart[2][1] + sPart[3][1];
        out[ray * 3 + 2] = sPart[0][2] + sPart[1][2] + sPart[2][2] + sPart[3][2];
    }
}

extern "C" void kernel_launch(void* const* d_in, const int* in_sizes, int n_in,
                              void* d_out, int out_size, void* d_ws, size_t ws_size,
                              hipStream_t stream) {
    const int n_rays = in_sizes[0] / 3;   // 4096
    nerf_prep<<<1, 256, 0, stream>>>(
        (const float*)d_in[3], (const float*)d_in[4], (const float*)d_in[5],
        (const float*)d_in[6], (const float*)d_in[7], (const float*)d_in[8],
        (const float*)d_in[9], (unsigned char*)d_ws);
    nerf_mfma<<<n_rays, 256, 0, stream>>>(
        (const float*)d_in[0],  (const float*)d_in[1],  (const float*)d_in[2],
        (const float*)d_in[6],  (const float*)d_in[9],  (const float*)d_in[10],
        (const float*)d_in[11], (const float*)d_in[12],
        (const unsigned char*)d_ws, (float*)d_out);
}